// Round 1
// baseline (1903.023 us; speedup 1.0000x reference)
//
#include <hip/hip_runtime.h>
#include <hip/hip_bf16.h>
#include <type_traits>

typedef unsigned short u16;
typedef unsigned int   u32;
typedef unsigned long long u64;
typedef __attribute__((ext_vector_type(8))) short short8;
typedef __attribute__((ext_vector_type(4))) float f32x4;

#define HID   4096
#define NHEAD 32
#define HD    128
#define NB    4
#define NSQ   2048
#define NSK   128
#define MROWS (NB*NSQ)   // 8192
#define KROWS (NB*NSK)   // 512

// ---------- helpers ----------
__device__ __forceinline__ u16 f2bf(float f) {           // RNE f32->bf16 (finite data)
  u32 u = __builtin_bit_cast(u32, f);
  u += 0x7fffu + ((u >> 16) & 1u);
  return (u16)(u >> 16);
}

__device__ __forceinline__ u64 pack4(float4 f) {
  return (u64)f2bf(f.x) | ((u64)f2bf(f.y) << 16) |
         ((u64)f2bf(f.z) << 32) | ((u64)f2bf(f.w) << 48);
}

__device__ __forceinline__ uint4 packu16x8(const u16* v) {
  uint4 o;
  o.x = (u32)v[0] | ((u32)v[1] << 16);
  o.y = (u32)v[2] | ((u32)v[3] << 16);
  o.z = (u32)v[4] | ((u32)v[5] << 16);
  o.w = (u32)v[6] | ((u32)v[7] << 16);
  return o;
}

__device__ __forceinline__ f32x4 mfma16(short8 a, short8 b, f32x4 c) {
  return __builtin_amdgcn_mfma_f32_16x16x32_bf16(a, b, c, 0, 0, 0);
}

__device__ __forceinline__ void gload_lds16(const u16* g, u16* l) {
  __builtin_amdgcn_global_load_lds((const __attribute__((address_space(1))) u32*)g,
                                   (__attribute__((address_space(3))) u32*)l, 16, 0, 0);
}

// ---------- W transpose + f32->bf16 convert: Wt[n][k] = bf16(W[k][n]) ----------
__global__ __launch_bounds__(256) void transpose_convert(const float* __restrict__ W,
                                                         u16* __restrict__ Wt)
{
  __shared__ __align__(16) u16 tile[64][72];
  const int t = threadIdx.x;
  const int c0 = blockIdx.x * 64, r0 = blockIdx.y * 64;
  #pragma unroll
  for (int i = 0; i < 4; ++i) {
    int e = i * 1024 + t * 4;
    int rr = e >> 6, cc = e & 63;
    float4 f = *(const float4*)(W + (size_t)(r0 + rr) * HID + c0 + cc);
    *(u64*)&tile[rr][cc] = pack4(f);
  }
  __syncthreads();
  #pragma unroll
  for (int i = 0; i < 2; ++i) {
    int e = i * 2048 + t * 8;
    int cc = e >> 6, rr = e & 63;
    u16 vals[8];
    #pragma unroll
    for (int jj = 0; jj < 8; ++jj) vals[jj] = tile[rr + jj][cc];
    *(uint4*)(Wt + (size_t)(c0 + cc) * HID + r0 + rr) = packu16x8(vals);
  }
}

// ---------- per-head transpose of Vh: VT[b,h,d,t] = Vh[b*128+t, h*128+d] ----------
__global__ __launch_bounds__(256) void transpose_head(const u16* __restrict__ Vh,
                                                      u16* __restrict__ VT)
{
  __shared__ __align__(16) u16 tile[128][136];
  const int t = threadIdx.x;
  const int bh = blockIdx.x;
  const int b = bh >> 5, h = bh & 31;
  #pragma unroll
  for (int i = 0; i < 8; ++i) {
    int e = i * 2048 + t * 8;
    int tr = e >> 7, d = e & 127;
    *(uint4*)&tile[tr][d] = *(const uint4*)(Vh + ((size_t)b * NSK + tr) * HID + h * HD + d);
  }
  __syncthreads();
  #pragma unroll
  for (int i = 0; i < 8; ++i) {
    int e = i * 2048 + t * 8;
    int d = e >> 7, tt = e & 127;
    u16 vals[8];
    #pragma unroll
    for (int jj = 0; jj < 8; ++jj) vals[jj] = tile[tt + jj][d];
    *(uint4*)(VT + ((size_t)bh * HD + d) * NSK + tt) = packu16x8(vals);
  }
}

// ---------- GEMM: C[M,N] = A[M,K] @ B[K,N], Bt stored as B^T [N][K] bf16 ----------
// 128x128 tile, BK=64, 4 waves (2x2 of 64x64), 16x16x32 bf16 MFMA.
template <typename TA, bool OUTF32>
__global__ __launch_bounds__(256) void gemm_bt(const TA* __restrict__ A,
                                               const u16* __restrict__ Bt,
                                               void* __restrict__ Cv,
                                               int M, int N, int K)
{
  __shared__ __align__(16) u16 As[128 * 64];
  __shared__ __align__(16) u16 Bs[128 * 64];
  const int t = threadIdx.x;
  const int w = t >> 6, l = t & 63;
  const int g = l >> 4, c16 = l & 15;
  const int m0 = blockIdx.y * 128, n0 = blockIdx.x * 128;
  const int wm = (w >> 1) * 64, wn = (w & 1) * 64;

  f32x4 acc[4][4] = {};

  for (int kt = 0; kt < K; kt += 64) {
    if constexpr (std::is_same<TA, float>::value) {
      // reg-staged f32 -> bf16 convert into LDS
      #pragma unroll
      for (int i = 0; i < 8; ++i) {
        int e = i * 1024 + t * 4;
        int rr = e >> 6, cc = e & 63;
        float4 f = *(const float4*)(A + (size_t)(m0 + rr) * K + kt + cc);
        *(u64*)(As + e) = pack4(f);
      }
    } else {
      // bf16 A: direct global->LDS async, 16B, linear lane layout
      #pragma unroll
      for (int i = 0; i < 4; ++i) {
        int e = i * 2048 + t * 8;
        int rr = e >> 6, cc = e & 63;
        gload_lds16((const u16*)A + (size_t)(m0 + rr) * K + kt + cc, As + e);
      }
    }
    #pragma unroll
    for (int i = 0; i < 4; ++i) {
      int e = i * 2048 + t * 8;
      int rr = e >> 6, cc = e & 63;
      gload_lds16(Bt + (size_t)(n0 + rr) * K + kt + cc, Bs + e);
    }
    __syncthreads();
    #pragma unroll
    for (int ks = 0; ks < 2; ++ks) {
      const int ko = ks * 32 + g * 8;
      short8 af[4], bfr[4];
      #pragma unroll
      for (int i = 0; i < 4; ++i)
        af[i] = *(const short8*)(As + (wm + i * 16 + c16) * 64 + ko);
      #pragma unroll
      for (int j = 0; j < 4; ++j)
        bfr[j] = *(const short8*)(Bs + (wn + j * 16 + c16) * 64 + ko);
      #pragma unroll
      for (int i = 0; i < 4; ++i)
        #pragma unroll
        for (int j = 0; j < 4; ++j)
          acc[i][j] = mfma16(af[i], bfr[j], acc[i][j]);
    }
    __syncthreads();
  }

  #pragma unroll
  for (int i = 0; i < 4; ++i)
    #pragma unroll
    for (int j = 0; j < 4; ++j)
      #pragma unroll
      for (int rr = 0; rr < 4; ++rr) {
        const size_t row = (size_t)m0 + wm + i * 16 + g * 4 + rr;
        const size_t col = (size_t)n0 + wn + j * 16 + c16;
        if constexpr (OUTF32)
          ((float*)Cv)[row * N + col] = acc[i][j][rr];
        else
          ((u16*)Cv)[row * N + col] = f2bf(acc[i][j][rr]);
      }
}

// ---------- fused attention: scores = Qh Kh^T * scale + Rh ; softmax ; @ Vh ----------
// grid: (16 q-chunks of 128, B*H). block: 256 thr / 4 waves, wave = 32 q rows.
__global__ __launch_bounds__(256) void attn_kernel(const u16*  __restrict__ Qh,
                                                   const u16*  __restrict__ Kh,
                                                   const u16*  __restrict__ VT,
                                                   const float* __restrict__ Rh,
                                                   u16* __restrict__ ctx)
{
  __shared__ __align__(16) u16 Plds[4][32][136];
  const int t = threadIdx.x;
  const int w = t >> 6, l = t & 63;
  const int g = l >> 4, c = l & 15;
  const int qc = blockIdx.x;
  const int bh = blockIdx.y;
  const int b = bh >> 5, h = bh & 31;
  const size_t qrow0 = (size_t)b * NSQ + qc * 128 + w * 32;
  const float SCALE = 0.08838834764831845f;  // 1/sqrt(128)

  // --- QK^T (M=32 per wave, N=128, K=128) ---
  f32x4 s[2][8] = {};
  #pragma unroll
  for (int ks = 0; ks < 4; ++ks) {
    const int ko = ks * 32 + g * 8;
    short8 af[2];
    #pragma unroll
    for (int i = 0; i < 2; ++i)
      af[i] = *(const short8*)(Qh + (qrow0 + i * 16 + c) * HID + h * HD + ko);
    #pragma unroll
    for (int j = 0; j < 8; ++j) {
      short8 bfr = *(const short8*)(Kh + ((size_t)b * NSK + j * 16 + c) * HID + h * HD + ko);
      s[0][j] = mfma16(af[0], bfr, s[0][j]);
      s[1][j] = mfma16(af[1], bfr, s[1][j]);
    }
  }

  // --- scale + bias + softmax (row r held by 16-lane group g, reg rr) ---
  float rinv[2][4];
  #pragma unroll
  for (int i = 0; i < 2; ++i) {
    #pragma unroll
    for (int rr = 0; rr < 4; ++rr) {
      const size_t qr = qrow0 + i * 16 + g * 4 + rr;
      float vmax = -3.0e38f;
      #pragma unroll
      for (int j = 0; j < 8; ++j) {
        float bias = Rh[qr * HID + h * HD + j * 16 + c];
        float sv = s[i][j][rr] * SCALE + bias;
        s[i][j][rr] = sv;
        vmax = fmaxf(vmax, sv);
      }
      #pragma unroll
      for (int m = 1; m < 16; m <<= 1) vmax = fmaxf(vmax, __shfl_xor(vmax, m));
      float ssum = 0.f;
      #pragma unroll
      for (int j = 0; j < 8; ++j) {
        float p = __expf(s[i][j][rr] - vmax);
        s[i][j][rr] = p;
        ssum += p;
      }
      #pragma unroll
      for (int m = 1; m < 16; m <<= 1) ssum += __shfl_xor(ssum, m);
      rinv[i][rr] = 1.f / ssum;
    }
  }

  // --- P -> LDS (bf16, unnormalized; divide after PV) ---
  #pragma unroll
  for (int i = 0; i < 2; ++i)
    #pragma unroll
    for (int j = 0; j < 8; ++j)
      #pragma unroll
      for (int rr = 0; rr < 4; ++rr)
        Plds[w][i * 16 + g * 4 + rr][j * 16 + c] = f2bf(s[i][j][rr]);
  __syncthreads();

  // --- PV (M=32, N=128, K=128), B = VT[b,h][d][t] ---
  #pragma unroll
  for (int i = 0; i < 2; ++i) {
    f32x4 o[8] = {};
    #pragma unroll
    for (int ks = 0; ks < 4; ++ks) {
      const int ko = ks * 32 + g * 8;
      short8 pa = *(const short8*)(&Plds[w][i * 16 + c][ko]);
      #pragma unroll
      for (int j = 0; j < 8; ++j) {
        short8 bv = *(const short8*)(VT + ((size_t)bh * HD + j * 16 + c) * NSK + ko);
        o[j] = mfma16(pa, bv, o[j]);
      }
    }
    #pragma unroll
    for (int j = 0; j < 8; ++j)
      #pragma unroll
      for (int rr = 0; rr < 4; ++rr) {
        const size_t row = qrow0 + i * 16 + g * 4 + rr;
        ctx[row * HID + h * HD + j * 16 + c] = f2bf(o[j][rr] * rinv[i][rr]);
      }
  }
}

// ---------- launch ----------
extern "C" void kernel_launch(void* const* d_in, const int* in_sizes, int n_in,
                              void* d_out, int out_size, void* d_ws, size_t ws_size,
                              hipStream_t stream)
{
  const float* q  = (const float*)d_in[0];
  const float* k  = (const float*)d_in[1];
  const float* v  = (const float*)d_in[2];
  const float* r  = (const float*)d_in[3];
  const float* Wq = (const float*)d_in[4];
  const float* Wk = (const float*)d_in[5];
  const float* Wv = (const float*)d_in[6];
  const float* Wo = (const float*)d_in[7];
  float* out = (float*)d_out;

  char* ws = (char*)d_ws;
  u16* WqT = (u16*)(ws);
  u16* WkT = (u16*)(ws + (1ULL << 25));
  u16* WvT = (u16*)(ws + (2ULL << 25));
  u16* WoT = (u16*)(ws + (3ULL << 25));
  u16* Qh  = (u16*)(ws + (4ULL << 25));                       // 64 MB
  u16* Kh  = (u16*)(ws + (6ULL << 25));                       // 4 MB
  u16* Vh  = (u16*)(ws + (6ULL << 25) + (4ULL << 20));        // 4 MB
  u16* VTb = (u16*)(ws + (6ULL << 25) + (8ULL << 20));        // 4 MB
  u16* ctx = (u16*)(ws + (6ULL << 25) + (12ULL << 20));       // 64 MB
  const size_t needed = (6ULL << 25) + (12ULL << 20) + (1ULL << 26);
  if (ws_size < needed) return;  // visible failure instead of OOB write

  dim3 tb(256);

  // W^T (bf16)
  transpose_convert<<<dim3(64, 64), tb, 0, stream>>>(Wq, WqT);
  transpose_convert<<<dim3(64, 64), tb, 0, stream>>>(Wk, WkT);
  transpose_convert<<<dim3(64, 64), tb, 0, stream>>>(Wv, WvT);
  transpose_convert<<<dim3(64, 64), tb, 0, stream>>>(Wo, WoT);

  // projections
  gemm_bt<float, false><<<dim3(32, 64), tb, 0, stream>>>(q, WqT, (void*)Qh, MROWS, HID, HID);
  gemm_bt<float, false><<<dim3(32, 4),  tb, 0, stream>>>(k, WkT, (void*)Kh, KROWS, HID, HID);
  gemm_bt<float, false><<<dim3(32, 4),  tb, 0, stream>>>(v, WvT, (void*)Vh, KROWS, HID, HID);
  // Rh (bias) -> d_out (f32), consumed by attention before final GEMM overwrites it
  gemm_bt<float, true><<<dim3(32, 64),  tb, 0, stream>>>(r, WoT, (void*)out, MROWS, HID, HID);

  transpose_head<<<dim3(128), tb, 0, stream>>>(Vh, VTb);

  attn_kernel<<<dim3(16, 128), tb, 0, stream>>>(Qh, Kh, VTb, out, ctx);

  // output projection
  gemm_bt<u16, true><<<dim3(32, 64), tb, 0, stream>>>(ctx, WoT, (void*)out, MROWS, HID, HID);
}

// Round 2
// 1736.712 us; speedup vs baseline: 1.0958x; 1.0958x over previous
//
#include <hip/hip_runtime.h>
#include <hip/hip_bf16.h>

typedef unsigned short u16;
typedef unsigned int   u32;
typedef unsigned long long u64;
typedef __attribute__((ext_vector_type(8))) short short8;
typedef __attribute__((ext_vector_type(4))) float f32x4;

#define HID   4096
#define NHEAD 32
#define HD    128
#define NB    4
#define NSQ   2048
#define NSK   128
#define MROWS (NB*NSQ)   // 8192
#define KROWS (NB*NSK)   // 512

// ---------- helpers ----------
__device__ __forceinline__ u16 f2bf(float f) {           // RNE f32->bf16 (finite data)
  u32 u = __builtin_bit_cast(u32, f);
  u += 0x7fffu + ((u >> 16) & 1u);
  return (u16)(u >> 16);
}

__device__ __forceinline__ u64 pack4(float4 f) {
  return (u64)f2bf(f.x) | ((u64)f2bf(f.y) << 16) |
         ((u64)f2bf(f.z) << 32) | ((u64)f2bf(f.w) << 48);
}

__device__ __forceinline__ uint4 packu16x8(const u16* v) {
  uint4 o;
  o.x = (u32)v[0] | ((u32)v[1] << 16);
  o.y = (u32)v[2] | ((u32)v[3] << 16);
  o.z = (u32)v[4] | ((u32)v[5] << 16);
  o.w = (u32)v[6] | ((u32)v[7] << 16);
  return o;
}

__device__ __forceinline__ f32x4 mfma16(short8 a, short8 b, f32x4 c) {
  return __builtin_amdgcn_mfma_f32_16x16x32_bf16(a, b, c, 0, 0, 0);
}

__device__ __forceinline__ void gload_lds16(const u16* g, u16* l) {
  __builtin_amdgcn_global_load_lds((const __attribute__((address_space(1))) u32*)g,
                                   (__attribute__((address_space(3))) u32*)l, 16, 0, 0);
}

// ---------- elementwise f32 -> bf16 (vectorized, grid-stride) ----------
__global__ __launch_bounds__(256) void convert_bf16(const float* __restrict__ in,
                                                    u16* __restrict__ out, long long n4)
{
  long long i = (long long)blockIdx.x * blockDim.x + threadIdx.x;
  const long long stride = (long long)gridDim.x * blockDim.x;
  for (; i < n4; i += stride) {
    float4 f = ((const float4*)in)[i];
    ((u64*)out)[i] = pack4(f);
  }
}

// ---------- W transpose + f32->bf16 convert: Wt[n][k] = bf16(W[k][n]) ----------
__global__ __launch_bounds__(256) void transpose_convert(const float* __restrict__ W,
                                                         u16* __restrict__ Wt)
{
  __shared__ __align__(16) u16 tile[64][72];
  const int t = threadIdx.x;
  const int c0 = blockIdx.x * 64, r0 = blockIdx.y * 64;
  #pragma unroll
  for (int i = 0; i < 4; ++i) {
    int e = i * 1024 + t * 4;
    int rr = e >> 6, cc = e & 63;
    float4 f = *(const float4*)(W + (size_t)(r0 + rr) * HID + c0 + cc);
    *(u64*)&tile[rr][cc] = pack4(f);
  }
  __syncthreads();
  #pragma unroll
  for (int i = 0; i < 2; ++i) {
    int e = i * 2048 + t * 8;
    int cc = e >> 6, rr = e & 63;
    u16 vals[8];
    #pragma unroll
    for (int jj = 0; jj < 8; ++jj) vals[jj] = tile[rr + jj][cc];
    *(uint4*)(Wt + (size_t)(c0 + cc) * HID + r0 + rr) = packu16x8(vals);
  }
}

// ---------- per-head transpose of Vh: VT[b,h,d,t] = Vh[b*128+t, h*128+d] ----------
__global__ __launch_bounds__(256) void transpose_head(const u16* __restrict__ Vh,
                                                      u16* __restrict__ VT)
{
  __shared__ __align__(16) u16 tile[128][136];
  const int t = threadIdx.x;
  const int bh = blockIdx.x;
  const int b = bh >> 5, h = bh & 31;
  #pragma unroll
  for (int i = 0; i < 8; ++i) {
    int e = i * 2048 + t * 8;
    int tr = e >> 7, d = e & 127;
    *(uint4*)&tile[tr][d] = *(const uint4*)(Vh + ((size_t)b * NSK + tr) * HID + h * HD + d);
  }
  __syncthreads();
  #pragma unroll
  for (int i = 0; i < 8; ++i) {
    int e = i * 2048 + t * 8;
    int d = e >> 7, tt = e & 127;
    u16 vals[8];
    #pragma unroll
    for (int jj = 0; jj < 8; ++jj) vals[jj] = tile[tt + jj][d];
    *(uint4*)(VT + ((size_t)bh * HD + d) * NSK + tt) = packu16x8(vals);
  }
}

// ---------- GEMM: C[M,N] = A[M,K] @ B[K,N]; A bf16 [M][K], Bt = B^T [N][K] bf16 ----------
// 128x128 tile, BK=64, 4 waves (2x2 of 64x64), 16x16x32 bf16 MFMA,
// global_load_lds x16 for BOTH tiles, bijective XCD blockIdx swizzle.
template <bool OUTF32>
__global__ __launch_bounds__(256) void gemm_bt(const u16* __restrict__ A,
                                               const u16* __restrict__ Bt,
                                               void* __restrict__ Cv,
                                               int M, int N, int K)
{
  __shared__ __align__(16) u16 As[128 * 64];
  __shared__ __align__(16) u16 Bs[128 * 64];
  const int t = threadIdx.x;
  const int w = t >> 6, l = t & 63;
  const int g = l >> 4, c16 = l & 15;

  // XCD-aware bijective swizzle (grids here always have nwg % 8 == 0)
  const int nwg = gridDim.x * gridDim.y;
  int wg = blockIdx.y * gridDim.x + blockIdx.x;
  wg = (wg & 7) * (nwg >> 3) + (wg >> 3);
  const int m0 = (wg / gridDim.x) * 128, n0 = (wg % gridDim.x) * 128;
  const int wm = (w >> 1) * 64, wn = (w & 1) * 64;

  f32x4 acc[4][4] = {};

  for (int kt = 0; kt < K; kt += 64) {
    #pragma unroll
    for (int i = 0; i < 4; ++i) {
      int e = i * 2048 + t * 8;
      int rr = e >> 6, cc = e & 63;
      gload_lds16(A + (size_t)(m0 + rr) * K + kt + cc, As + e);
      gload_lds16(Bt + (size_t)(n0 + rr) * K + kt + cc, Bs + e);
    }
    __syncthreads();
    #pragma unroll
    for (int ks = 0; ks < 2; ++ks) {
      const int ko = ks * 32 + g * 8;
      short8 af[4], bfr[4];
      #pragma unroll
      for (int i = 0; i < 4; ++i)
        af[i] = *(const short8*)(As + (wm + i * 16 + c16) * 64 + ko);
      #pragma unroll
      for (int j = 0; j < 4; ++j)
        bfr[j] = *(const short8*)(Bs + (wn + j * 16 + c16) * 64 + ko);
      #pragma unroll
      for (int i = 0; i < 4; ++i)
        #pragma unroll
        for (int j = 0; j < 4; ++j)
          acc[i][j] = mfma16(af[i], bfr[j], acc[i][j]);
    }
    __syncthreads();
  }

  #pragma unroll
  for (int i = 0; i < 4; ++i)
    #pragma unroll
    for (int j = 0; j < 4; ++j)
      #pragma unroll
      for (int rr = 0; rr < 4; ++rr) {
        const size_t row = (size_t)m0 + wm + i * 16 + g * 4 + rr;
        const size_t col = (size_t)n0 + wn + j * 16 + c16;
        if constexpr (OUTF32)
          ((float*)Cv)[row * N + col] = acc[i][j][rr];
        else
          ((u16*)Cv)[row * N + col] = f2bf(acc[i][j][rr]);
      }
}

// ---------- fused attention: scores = Qh Kh^T * scale + Rh ; softmax ; @ Vh ----------
// grid: (16 q-chunks of 128, B*H). block: 256 thr / 4 waves, wave = 32 q rows.
__global__ __launch_bounds__(256) void attn_kernel(const u16*  __restrict__ Qh,
                                                   const u16*  __restrict__ Kh,
                                                   const u16*  __restrict__ VT,
                                                   const float* __restrict__ Rh,
                                                   u16* __restrict__ ctx)
{
  __shared__ __align__(16) u16 Plds[4][32][136];
  const int t = threadIdx.x;
  const int w = t >> 6, l = t & 63;
  const int g = l >> 4, c = l & 15;
  const int qc = blockIdx.x;
  const int bh = blockIdx.y;
  const int b = bh >> 5, h = bh & 31;
  const size_t qrow0 = (size_t)b * NSQ + qc * 128 + w * 32;
  const float SCALE = 0.08838834764831845f;  // 1/sqrt(128)

  // --- QK^T (M=32 per wave, N=128, K=128) ---
  f32x4 s[2][8] = {};
  #pragma unroll
  for (int ks = 0; ks < 4; ++ks) {
    const int ko = ks * 32 + g * 8;
    short8 af[2];
    #pragma unroll
    for (int i = 0; i < 2; ++i)
      af[i] = *(const short8*)(Qh + (qrow0 + i * 16 + c) * HID + h * HD + ko);
    #pragma unroll
    for (int j = 0; j < 8; ++j) {
      short8 bfr = *(const short8*)(Kh + ((size_t)b * NSK + j * 16 + c) * HID + h * HD + ko);
      s[0][j] = mfma16(af[0], bfr, s[0][j]);
      s[1][j] = mfma16(af[1], bfr, s[1][j]);
    }
  }

  // --- scale + bias + softmax (row r held by 16-lane group g, reg rr) ---
  float rinv[2][4];
  #pragma unroll
  for (int i = 0; i < 2; ++i) {
    #pragma unroll
    for (int rr = 0; rr < 4; ++rr) {
      const size_t qr = qrow0 + i * 16 + g * 4 + rr;
      float vmax = -3.0e38f;
      #pragma unroll
      for (int j = 0; j < 8; ++j) {
        float bias = Rh[qr * HID + h * HD + j * 16 + c];
        float sv = s[i][j][rr] * SCALE + bias;
        s[i][j][rr] = sv;
        vmax = fmaxf(vmax, sv);
      }
      #pragma unroll
      for (int m = 1; m < 16; m <<= 1) vmax = fmaxf(vmax, __shfl_xor(vmax, m));
      float ssum = 0.f;
      #pragma unroll
      for (int j = 0; j < 8; ++j) {
        float p = __expf(s[i][j][rr] - vmax);
        s[i][j][rr] = p;
        ssum += p;
      }
      #pragma unroll
      for (int m = 1; m < 16; m <<= 1) ssum += __shfl_xor(ssum, m);
      rinv[i][rr] = 1.f / ssum;
    }
  }

  // --- P -> LDS (bf16, unnormalized; divide after PV) ---
  #pragma unroll
  for (int i = 0; i < 2; ++i)
    #pragma unroll
    for (int j = 0; j < 8; ++j)
      #pragma unroll
      for (int rr = 0; rr < 4; ++rr)
        Plds[w][i * 16 + g * 4 + rr][j * 16 + c] = f2bf(s[i][j][rr]);
  __syncthreads();

  // --- PV (M=32, N=128, K=128), B = VT[b,h][d][t] ---
  #pragma unroll
  for (int i = 0; i < 2; ++i) {
    f32x4 o[8] = {};
    #pragma unroll
    for (int ks = 0; ks < 4; ++ks) {
      const int ko = ks * 32 + g * 8;
      short8 pa = *(const short8*)(&Plds[w][i * 16 + c][ko]);
      #pragma unroll
      for (int j = 0; j < 8; ++j) {
        short8 bv = *(const short8*)(VT + ((size_t)bh * HD + j * 16 + c) * NSK + ko);
        o[j] = mfma16(pa, bv, o[j]);
      }
    }
    #pragma unroll
    for (int j = 0; j < 8; ++j)
      #pragma unroll
      for (int rr = 0; rr < 4; ++rr) {
        const size_t row = qrow0 + i * 16 + g * 4 + rr;
        ctx[row * HID + h * HD + j * 16 + c] = f2bf(o[j][rr] * rinv[i][rr]);
      }
  }
}

// ---------- launch ----------
extern "C" void kernel_launch(void* const* d_in, const int* in_sizes, int n_in,
                              void* d_out, int out_size, void* d_ws, size_t ws_size,
                              hipStream_t stream)
{
  const float* q  = (const float*)d_in[0];
  const float* k  = (const float*)d_in[1];
  const float* v  = (const float*)d_in[2];
  const float* r  = (const float*)d_in[3];
  const float* Wq = (const float*)d_in[4];
  const float* Wk = (const float*)d_in[5];
  const float* Wv = (const float*)d_in[6];
  const float* Wo = (const float*)d_in[7];
  float* out = (float*)d_out;

  // Workspace layout with lifetime-based aliasing (total 268 MB, known-good):
  //  [0,32)    WoT        (lives to the end)
  //  [32,96)   Qh         (to attn)
  //  [96,100)  Kh         (to attn)
  //  [100,104) Vh         (to transpose_head)
  //  [104,108) VT         (to attn)
  //  [108,172) ctx        (attn -> final GEMM); kb@108 / vb@112 die before attn
  //  [172,236) Sb         (qb for Qh-GEMM, then rb for Rh-GEMM)
  //  [236,268) Wt         (WqT, then WkT, then WvT — sequential reuse)
  char* ws = (char*)d_ws;
  #define WSMB(x) ((size_t)(x) << 20)
  u16* WoT = (u16*)(ws + WSMB(0));
  u16* Qh  = (u16*)(ws + WSMB(32));
  u16* Kh  = (u16*)(ws + WSMB(96));
  u16* Vh  = (u16*)(ws + WSMB(100));
  u16* VTb = (u16*)(ws + WSMB(104));
  u16* ctx = (u16*)(ws + WSMB(108));
  u16* kb  = (u16*)(ws + WSMB(108));
  u16* vb  = (u16*)(ws + WSMB(112));
  u16* Sb  = (u16*)(ws + WSMB(172));
  u16* Wt  = (u16*)(ws + WSMB(236));
  const size_t needed = WSMB(268);
  if (ws_size < needed) return;  // visible failure instead of OOB write

  dim3 tb(256);
  const long long nBig = (long long)MROWS * HID / 4;   // q/r element-quads
  const long long nSm  = (long long)KROWS * HID / 4;   // k/v element-quads

  transpose_convert<<<dim3(64, 64), tb, 0, stream>>>(Wo, WoT);

  // Qh = bf16(q) @ WqT
  convert_bf16<<<dim3(2048), tb, 0, stream>>>(q, Sb, nBig);
  transpose_convert<<<dim3(64, 64), tb, 0, stream>>>(Wq, Wt);
  gemm_bt<false><<<dim3(32, 64), tb, 0, stream>>>(Sb, Wt, (void*)Qh, MROWS, HID, HID);

  // Rh = bf16(r) @ WoT -> d_out (f32 bias, consumed by attn before final GEMM)
  convert_bf16<<<dim3(2048), tb, 0, stream>>>(r, Sb, nBig);
  gemm_bt<true><<<dim3(32, 64), tb, 0, stream>>>(Sb, WoT, (void*)out, MROWS, HID, HID);

  // Kh = bf16(k) @ WkT ; Vh = bf16(v) @ WvT
  convert_bf16<<<dim3(512), tb, 0, stream>>>(k, kb, nSm);
  transpose_convert<<<dim3(64, 64), tb, 0, stream>>>(Wk, Wt);
  gemm_bt<false><<<dim3(32, 4), tb, 0, stream>>>(kb, Wt, (void*)Kh, KROWS, HID, HID);
  convert_bf16<<<dim3(512), tb, 0, stream>>>(v, vb, nSm);
  transpose_convert<<<dim3(64, 64), tb, 0, stream>>>(Wv, Wt);
  gemm_bt<false><<<dim3(32, 4), tb, 0, stream>>>(vb, Wt, (void*)Vh, KROWS, HID, HID);

  transpose_head<<<dim3(128), tb, 0, stream>>>(Vh, VTb);

  attn_kernel<<<dim3(16, 128), tb, 0, stream>>>(Qh, Kh, VTb, out, ctx);

  // out = ctx @ WoT
  gemm_bt<true><<<dim3(32, 64), tb, 0, stream>>>(ctx, WoT, (void*)out, MROWS, HID, HID);
}

// Round 3
// 1181.220 us; speedup vs baseline: 1.6111x; 1.4703x over previous
//
#include <hip/hip_runtime.h>
#include <hip/hip_bf16.h>

typedef unsigned short u16;
typedef unsigned int   u32;
typedef unsigned long long u64;
typedef __attribute__((ext_vector_type(8))) short short8;
typedef __attribute__((ext_vector_type(4))) float f32x4;

#define HID   4096
#define NHEAD 32
#define HD    128
#define NB    4
#define NSQ   2048
#define NSK   128
#define MROWS (NB*NSQ)   // 8192
#define KROWS (NB*NSK)   // 512

// ---------- helpers ----------
__device__ __forceinline__ u16 f2bf(float f) {           // RNE f32->bf16 (finite data)
  u32 u = __builtin_bit_cast(u32, f);
  u += 0x7fffu + ((u >> 16) & 1u);
  return (u16)(u >> 16);
}

__device__ __forceinline__ u64 pack4(float4 f) {
  return (u64)f2bf(f.x) | ((u64)f2bf(f.y) << 16) |
         ((u64)f2bf(f.z) << 32) | ((u64)f2bf(f.w) << 48);
}

__device__ __forceinline__ uint4 packu16x8(const u16* v) {
  uint4 o;
  o.x = (u32)v[0] | ((u32)v[1] << 16);
  o.y = (u32)v[2] | ((u32)v[3] << 16);
  o.z = (u32)v[4] | ((u32)v[5] << 16);
  o.w = (u32)v[6] | ((u32)v[7] << 16);
  return o;
}

__device__ __forceinline__ f32x4 mfma16(short8 a, short8 b, f32x4 c) {
  return __builtin_amdgcn_mfma_f32_16x16x32_bf16(a, b, c, 0, 0, 0);
}

__device__ __forceinline__ void gload_lds16(const u16* g, u16* l) {
  __builtin_amdgcn_global_load_lds((const __attribute__((address_space(1))) u32*)g,
                                   (__attribute__((address_space(3))) u32*)l, 16, 0, 0);
}

// ---------- elementwise f32 -> bf16 ----------
__global__ __launch_bounds__(256) void convert_bf16(const float* __restrict__ in,
                                                    u16* __restrict__ out, long long n4)
{
  long long i = (long long)blockIdx.x * blockDim.x + threadIdx.x;
  const long long stride = (long long)gridDim.x * blockDim.x;
  for (; i < n4; i += stride) {
    float4 f = ((const float4*)in)[i];
    ((u64*)out)[i] = pack4(f);
  }
}

// ---------- W transpose + convert: Wt[n][k] = bf16(W[k][n]) ----------
__global__ __launch_bounds__(256) void transpose_convert(const float* __restrict__ W,
                                                         u16* __restrict__ Wt)
{
  __shared__ __align__(16) u16 tile[64][72];
  const int t = threadIdx.x;
  const int c0 = blockIdx.x * 64, r0 = blockIdx.y * 64;
  #pragma unroll
  for (int i = 0; i < 4; ++i) {
    int e = i * 1024 + t * 4;
    int rr = e >> 6, cc = e & 63;
    float4 f = *(const float4*)(W + (size_t)(r0 + rr) * HID + c0 + cc);
    *(u64*)&tile[rr][cc] = pack4(f);
  }
  __syncthreads();
  #pragma unroll
  for (int i = 0; i < 2; ++i) {
    int e = i * 2048 + t * 8;
    int cc = e >> 6, rr = e & 63;
    u16 vals[8];
    #pragma unroll
    for (int jj = 0; jj < 8; ++jj) vals[jj] = tile[rr + jj][cc];
    *(uint4*)(Wt + (size_t)(c0 + cc) * HID + r0 + rr) = packu16x8(vals);
  }
}

// ---------- per-head transpose of Vh ----------
__global__ __launch_bounds__(256) void transpose_head(const u16* __restrict__ Vh,
                                                      u16* __restrict__ VT)
{
  __shared__ __align__(16) u16 tile[128][136];
  const int t = threadIdx.x;
  const int bh = blockIdx.x;
  const int b = bh >> 5, h = bh & 31;
  #pragma unroll
  for (int i = 0; i < 8; ++i) {
    int e = i * 2048 + t * 8;
    int tr = e >> 7, d = e & 127;
    *(uint4*)&tile[tr][d] = *(const uint4*)(Vh + ((size_t)b * NSK + tr) * HID + h * HD + d);
  }
  __syncthreads();
  #pragma unroll
  for (int i = 0; i < 8; ++i) {
    int e = i * 2048 + t * 8;
    int d = e >> 7, tt = e & 127;
    u16 vals[8];
    #pragma unroll
    for (int jj = 0; jj < 8; ++jj) vals[jj] = tile[tt + jj][d];
    *(uint4*)(VT + ((size_t)bh * HD + d) * NSK + tt) = packu16x8(vals);
  }
}

// ====================== 256x256 8-phase GEMM (K = HID) ======================
// A [M][HID] bf16, Bt = B^T [HID... wait N=HID][HID] bf16, C [M][HID].
// 8 waves (2Mx4N), BK=64, 128KB LDS dbuf, T2 slot-XOR swizzle, counted vmcnt.

// LDS fragment read with slot-XOR swizzle: element col' = cb ^ ((r&7)*8)
__device__ __forceinline__ short8 ldf(const u16* buf, int r, int cb) {
  return *(const short8*)(buf + r * 64 + (cb ^ ((r & 7) << 3)));
}

// stage one half-tile (128 rows x 64 cols) into linear LDS with pre-swizzled src
__device__ __forceinline__ void stage2(u16* dst, const u16* g, long off0, long off1, int tid) {
  gload_lds16(g + off0, dst + tid * 8);
  gload_lds16(g + off1, dst + 4096 + tid * 8);
}

template<bool S1, bool S2, int VM>
__device__ __forceinline__ void tile8(const u16* __restrict__ Ag, const u16* __restrict__ Bg,
                                      int kt, u16* Ac, u16* Bc, u16* Ao, u16* Bo,
                                      int wm, int wn, int g, int c16,
                                      long off0, long off1, int tid, f32x4 (&acc)[8][4])
{
  const int g8 = g * 8;
  short8 af[4][2], bf[4][2];

  // ---- phase 1: quad (Mlo, Nlo) ----
  #pragma unroll
  for (int i = 0; i < 4; ++i) {
    const int r = wm * 128 + i * 16 + c16;
    af[i][0] = ldf(Ac, r, g8); af[i][1] = ldf(Ac, r, 32 + g8);
  }
  #pragma unroll
  for (int j = 0; j < 2; ++j) {
    const int r = wn * 64 + j * 16 + c16;
    bf[j][0] = ldf(Bc, r, g8); bf[j][1] = ldf(Bc, r, 32 + g8);
  }
  if constexpr (S1) stage2(Ao + 8192, Ag + (size_t)128 * HID + kt + 64, off0, off1, tid);
  __builtin_amdgcn_s_barrier();
  asm volatile("s_waitcnt lgkmcnt(0)" ::: "memory");
  __builtin_amdgcn_sched_barrier(0);
  __builtin_amdgcn_s_setprio(1);
  #pragma unroll
  for (int i = 0; i < 4; ++i)
    #pragma unroll
    for (int j = 0; j < 2; ++j) {
      acc[i][j] = mfma16(af[i][0], bf[j][0], acc[i][j]);
      acc[i][j] = mfma16(af[i][1], bf[j][1], acc[i][j]);
    }
  __builtin_amdgcn_s_setprio(0);
  __builtin_amdgcn_s_barrier();

  // ---- phase 2: quad (Mlo, Nhi) ----
  #pragma unroll
  for (int j = 2; j < 4; ++j) {
    const int r = wn * 64 + j * 16 + c16;
    bf[j][0] = ldf(Bc, r, g8); bf[j][1] = ldf(Bc, r, 32 + g8);
  }
  if constexpr (S1) stage2(Bo + 8192, Bg + (size_t)128 * HID + kt + 64, off0, off1, tid);
  __builtin_amdgcn_s_barrier();
  asm volatile("s_waitcnt lgkmcnt(0)" ::: "memory");
  __builtin_amdgcn_sched_barrier(0);
  __builtin_amdgcn_s_setprio(1);
  #pragma unroll
  for (int i = 0; i < 4; ++i)
    #pragma unroll
    for (int j = 2; j < 4; ++j) {
      acc[i][j] = mfma16(af[i][0], bf[j][0], acc[i][j]);
      acc[i][j] = mfma16(af[i][1], bf[j][1], acc[i][j]);
    }
  __builtin_amdgcn_s_setprio(0);
  __builtin_amdgcn_s_barrier();

  // ---- phase 3: quad (Mhi, Nlo) ----  (B0 region of current buf is dead now)
  #pragma unroll
  for (int i = 0; i < 4; ++i) {
    const int r = wm * 128 + 64 + i * 16 + c16;
    af[i][0] = ldf(Ac, r, g8); af[i][1] = ldf(Ac, r, 32 + g8);
  }
  if constexpr (S2) stage2(Bc, Bg + kt + 128, off0, off1, tid);
  __builtin_amdgcn_s_barrier();
  asm volatile("s_waitcnt lgkmcnt(0)" ::: "memory");
  __builtin_amdgcn_sched_barrier(0);
  __builtin_amdgcn_s_setprio(1);
  #pragma unroll
  for (int i = 0; i < 4; ++i)
    #pragma unroll
    for (int j = 0; j < 2; ++j) {
      acc[4 + i][j] = mfma16(af[i][0], bf[j][0], acc[4 + i][j]);
      acc[4 + i][j] = mfma16(af[i][1], bf[j][1], acc[4 + i][j]);
    }
  __builtin_amdgcn_s_setprio(0);
  __builtin_amdgcn_s_barrier();

  // ---- phase 4: quad (Mhi, Nhi) ----  (A region of current buf is dead now)
  if constexpr (S2) stage2(Ac, Ag + kt + 128, off0, off1, tid);
  __builtin_amdgcn_s_barrier();
  __builtin_amdgcn_s_setprio(1);
  #pragma unroll
  for (int i = 0; i < 4; ++i)
    #pragma unroll
    for (int j = 2; j < 4; ++j) {
      acc[4 + i][j] = mfma16(af[i][0], bf[j][0], acc[4 + i][j]);
      acc[4 + i][j] = mfma16(af[i][1], bf[j][1], acc[4 + i][j]);
    }
  __builtin_amdgcn_s_setprio(0);
  if constexpr (VM == 4) {
    asm volatile("s_waitcnt vmcnt(4)" ::: "memory");
    __builtin_amdgcn_sched_barrier(0);
  } else if constexpr (VM == 0) {
    asm volatile("s_waitcnt vmcnt(0)" ::: "memory");
    __builtin_amdgcn_sched_barrier(0);
  }
  __builtin_amdgcn_s_barrier();
}

template<bool OUTF32>
__global__ __launch_bounds__(512, 2) void gemm256(const u16* __restrict__ A,
                                                  const u16* __restrict__ Bt,
                                                  void* __restrict__ Cv)
{
  __shared__ __align__(16) u16 As[2][16384];
  __shared__ __align__(16) u16 Bs[2][16384];
  const int tid = threadIdx.x;
  const int l = tid & 63, wv = tid >> 6;
  const int g = (l >> 4) & 3, c16 = l & 15;
  const int wm = wv >> 2, wn = wv & 3;

  const int ntn = gridDim.x;
  const int nwg = gridDim.x * gridDim.y;
  int wg = blockIdx.y * gridDim.x + blockIdx.x;
  wg = (wg & 7) * (nwg >> 3) + (wg >> 3);          // bijective XCD swizzle (nwg%8==0)
  const int m0 = (wg / ntn) * 256, n0 = (wg % ntn) * 256;

  const u16* Ag = A + (size_t)m0 * HID;
  const u16* Bg = Bt + (size_t)n0 * HID;
  // per-thread staging source offsets (inverse slot-XOR swizzle)
  const long off0 = (long)(tid >> 3) * HID + (((tid & 7) ^ ((tid >> 3) & 7)) * 8);
  const long off1 = off0 + (long)64 * HID;

  f32x4 acc[8][4] = {};

  // prologue: T0.B0, T0.A0, T0.A1, T0.B1, T1.B0, T1.A0 ; vmcnt(4) -> T0 landed
  stage2(&Bs[0][0],    Bg,                     off0, off1, tid);
  stage2(&As[0][0],    Ag,                     off0, off1, tid);
  stage2(&As[0][8192], Ag + (size_t)128 * HID, off0, off1, tid);
  stage2(&Bs[0][8192], Bg + (size_t)128 * HID, off0, off1, tid);
  stage2(&Bs[1][0],    Bg + 64,                off0, off1, tid);
  stage2(&As[1][0],    Ag + 64,                off0, off1, tid);
  asm volatile("s_waitcnt vmcnt(4)" ::: "memory");
  __builtin_amdgcn_sched_barrier(0);
  __builtin_amdgcn_s_barrier();

  constexpr int NT = HID / 64;   // 64
  int T = 0;
  for (; T < NT - 3; T += 2) {
    tile8<true, true, 4>(Ag, Bg, T * 64,      &As[0][0], &Bs[0][0], &As[1][0], &Bs[1][0],
                         wm, wn, g, c16, off0, off1, tid, acc);
    tile8<true, true, 4>(Ag, Bg, T * 64 + 64, &As[1][0], &Bs[1][0], &As[0][0], &Bs[0][0],
                         wm, wn, g, c16, off0, off1, tid, acc);
  }
  tile8<true, false, 0>(Ag, Bg, (NT - 2) * 64, &As[0][0], &Bs[0][0], &As[1][0], &Bs[1][0],
                        wm, wn, g, c16, off0, off1, tid, acc);
  tile8<false, false, -1>(Ag, Bg, (NT - 1) * 64, &As[1][0], &Bs[1][0], &As[0][0], &Bs[0][0],
                          wm, wn, g, c16, off0, off1, tid, acc);

  #pragma unroll
  for (int mi = 0; mi < 8; ++mi)
    #pragma unroll
    for (int j = 0; j < 4; ++j)
      #pragma unroll
      for (int rr = 0; rr < 4; ++rr) {
        const size_t row = (size_t)m0 + wm * 128 + mi * 16 + g * 4 + rr;
        const size_t col = (size_t)n0 + wn * 64 + j * 16 + c16;
        if constexpr (OUTF32)
          ((float*)Cv)[row * HID + col] = acc[mi][j][rr];
        else
          ((u16*)Cv)[row * HID + col] = f2bf(acc[mi][j][rr]);
      }
}

// ---------- fused K+V projection: A = [kb;vb] [1024][HID], 128x128 2-phase ----------
__global__ __launch_bounds__(256) void gemm_kv(const u16* __restrict__ A,
                                               const u16* __restrict__ WkTp,
                                               const u16* __restrict__ WvTp,
                                               u16* __restrict__ Kh,
                                               u16* __restrict__ Vh)
{
  __shared__ __align__(16) u16 As_[128 * 64];
  __shared__ __align__(16) u16 Bs_[128 * 64];
  const int t = threadIdx.x;
  const int w = t >> 6, l = t & 63;
  const int g = l >> 4, c16 = l & 15;
  const int m0 = blockIdx.y * 128, n0 = blockIdx.x * 128;
  const u16* Bt = (m0 < 512) ? WkTp : WvTp;
  u16* C = (m0 < 512) ? Kh : Vh;
  const int mr0 = m0 & 511;
  const int wm = (w >> 1) * 64, wn = (w & 1) * 64;

  f32x4 acc[4][4] = {};
  for (int kt = 0; kt < HID; kt += 64) {
    #pragma unroll
    for (int i = 0; i < 4; ++i) {
      int e = i * 2048 + t * 8;
      int rr = e >> 6, cc = e & 63;
      gload_lds16(A + (size_t)(m0 + rr) * HID + kt + cc, As_ + e);
      gload_lds16(Bt + (size_t)(n0 + rr) * HID + kt + cc, Bs_ + e);
    }
    __syncthreads();
    #pragma unroll
    for (int ks = 0; ks < 2; ++ks) {
      const int ko = ks * 32 + g * 8;
      short8 af2[4], bf2[4];
      #pragma unroll
      for (int i = 0; i < 4; ++i)
        af2[i] = *(const short8*)(As_ + (wm + i * 16 + c16) * 64 + ko);
      #pragma unroll
      for (int j = 0; j < 4; ++j)
        bf2[j] = *(const short8*)(Bs_ + (wn + j * 16 + c16) * 64 + ko);
      #pragma unroll
      for (int i = 0; i < 4; ++i)
        #pragma unroll
        for (int j = 0; j < 4; ++j)
          acc[i][j] = mfma16(af2[i], bf2[j], acc[i][j]);
    }
    __syncthreads();
  }
  #pragma unroll
  for (int i = 0; i < 4; ++i)
    #pragma unroll
    for (int j = 0; j < 4; ++j)
      #pragma unroll
      for (int rr = 0; rr < 4; ++rr)
        C[(size_t)(mr0 + wm + i * 16 + g * 4 + rr) * HID + n0 + wn + j * 16 + c16] =
            f2bf(acc[i][j][rr]);
}

// ---------- fused attention (unchanged) ----------
__global__ __launch_bounds__(256) void attn_kernel(const u16*  __restrict__ Qh,
                                                   const u16*  __restrict__ Kh,
                                                   const u16*  __restrict__ VT,
                                                   const float* __restrict__ Rh,
                                                   u16* __restrict__ ctx)
{
  __shared__ __align__(16) u16 Plds[4][32][136];
  const int t = threadIdx.x;
  const int w = t >> 6, l = t & 63;
  const int g = l >> 4, c = l & 15;
  const int qc = blockIdx.x;
  const int bh = blockIdx.y;
  const int b = bh >> 5, h = bh & 31;
  const size_t qrow0 = (size_t)b * NSQ + qc * 128 + w * 32;
  const float SCALE = 0.08838834764831845f;  // 1/sqrt(128)

  f32x4 s[2][8] = {};
  #pragma unroll
  for (int ks = 0; ks < 4; ++ks) {
    const int ko = ks * 32 + g * 8;
    short8 af[2];
    #pragma unroll
    for (int i = 0; i < 2; ++i)
      af[i] = *(const short8*)(Qh + (qrow0 + i * 16 + c) * HID + h * HD + ko);
    #pragma unroll
    for (int j = 0; j < 8; ++j) {
      short8 bfr = *(const short8*)(Kh + ((size_t)b * NSK + j * 16 + c) * HID + h * HD + ko);
      s[0][j] = mfma16(af[0], bfr, s[0][j]);
      s[1][j] = mfma16(af[1], bfr, s[1][j]);
    }
  }

  float rinv[2][4];
  #pragma unroll
  for (int i = 0; i < 2; ++i) {
    #pragma unroll
    for (int rr = 0; rr < 4; ++rr) {
      const size_t qr = qrow0 + i * 16 + g * 4 + rr;
      float vmax = -3.0e38f;
      #pragma unroll
      for (int j = 0; j < 8; ++j) {
        float bias = Rh[qr * HID + h * HD + j * 16 + c];
        float sv = s[i][j][rr] * SCALE + bias;
        s[i][j][rr] = sv;
        vmax = fmaxf(vmax, sv);
      }
      #pragma unroll
      for (int m = 1; m < 16; m <<= 1) vmax = fmaxf(vmax, __shfl_xor(vmax, m));
      float ssum = 0.f;
      #pragma unroll
      for (int j = 0; j < 8; ++j) {
        float p = __expf(s[i][j][rr] - vmax);
        s[i][j][rr] = p;
        ssum += p;
      }
      #pragma unroll
      for (int m = 1; m < 16; m <<= 1) ssum += __shfl_xor(ssum, m);
      rinv[i][rr] = 1.f / ssum;
    }
  }

  #pragma unroll
  for (int i = 0; i < 2; ++i)
    #pragma unroll
    for (int j = 0; j < 8; ++j)
      #pragma unroll
      for (int rr = 0; rr < 4; ++rr)
        Plds[w][i * 16 + g * 4 + rr][j * 16 + c] = f2bf(s[i][j][rr]);
  __syncthreads();

  #pragma unroll
  for (int i = 0; i < 2; ++i) {
    f32x4 o[8] = {};
    #pragma unroll
    for (int ks = 0; ks < 4; ++ks) {
      const int ko = ks * 32 + g * 8;
      short8 pa = *(const short8*)(&Plds[w][i * 16 + c][ko]);
      #pragma unroll
      for (int j = 0; j < 8; ++j) {
        short8 bv = *(const short8*)(VT + ((size_t)bh * HD + j * 16 + c) * NSK + ko);
        o[j] = mfma16(pa, bv, o[j]);
      }
    }
    #pragma unroll
    for (int j = 0; j < 8; ++j)
      #pragma unroll
      for (int rr = 0; rr < 4; ++rr) {
        const size_t row = qrow0 + i * 16 + g * 4 + rr;
        ctx[row * HID + h * HD + j * 16 + c] = f2bf(o[j][rr] * rinv[i][rr]);
      }
  }
}

// ---------- launch ----------
extern "C" void kernel_launch(void* const* d_in, const int* in_sizes, int n_in,
                              void* d_out, int out_size, void* d_ws, size_t ws_size,
                              hipStream_t stream)
{
  const float* q  = (const float*)d_in[0];
  const float* k  = (const float*)d_in[1];
  const float* v  = (const float*)d_in[2];
  const float* r  = (const float*)d_in[3];
  const float* Wq = (const float*)d_in[4];
  const float* Wk = (const float*)d_in[5];
  const float* Wv = (const float*)d_in[6];
  const float* Wo = (const float*)d_in[7];
  float* out = (float*)d_out;

  // Workspace (268 MB, lifetime-aliased):
  //  [0,32)    WoT (whole run)      [32,96)  Qh        [96,100) Kh
  //  [100,104) Vh                   [104,108) VT
  //  [108,172) ctx  (kb@108, vb@112 die before attn writes ctx)
  //  [172,236) Sb (q-bf16 then r-bf16); after Rh-GEMM: WkT@172, WvT@204
  //  [236,268) WqT
  char* ws = (char*)d_ws;
  #define WSMB(x) ((size_t)(x) << 20)
  u16* WoT = (u16*)(ws + WSMB(0));
  u16* Qh  = (u16*)(ws + WSMB(32));
  u16* Kh  = (u16*)(ws + WSMB(96));
  u16* Vh  = (u16*)(ws + WSMB(100));
  u16* VTb = (u16*)(ws + WSMB(104));
  u16* ctx = (u16*)(ws + WSMB(108));
  u16* kb  = (u16*)(ws + WSMB(108));
  u16* vb  = (u16*)(ws + WSMB(112));
  u16* Sb  = (u16*)(ws + WSMB(172));
  u16* WkT = (u16*)(ws + WSMB(172));
  u16* WvT = (u16*)(ws + WSMB(204));
  u16* WqT = (u16*)(ws + WSMB(236));
  const size_t needed = WSMB(268);
  if (ws_size < needed) return;

  dim3 tb(256);
  dim3 tb5(512);
  const long long nBig = (long long)MROWS * HID / 4;
  const long long nSm  = (long long)KROWS * HID / 4;

  transpose_convert<<<dim3(64, 64), tb, 0, stream>>>(Wo, WoT);

  // Qh = bf16(q) @ WqT
  convert_bf16<<<dim3(2048), tb, 0, stream>>>(q, Sb, nBig);
  transpose_convert<<<dim3(64, 64), tb, 0, stream>>>(Wq, WqT);
  gemm256<false><<<dim3(16, 32), tb5, 0, stream>>>(Sb, WqT, (void*)Qh);

  // Rh = bf16(r) @ WoT -> d_out (f32 bias)
  convert_bf16<<<dim3(2048), tb, 0, stream>>>(r, Sb, nBig);
  gemm256<true><<<dim3(16, 32), tb5, 0, stream>>>(Sb, WoT, (void*)out);

  // K/V projections (fused, full occupancy)
  convert_bf16<<<dim3(512), tb, 0, stream>>>(k, kb, nSm);
  convert_bf16<<<dim3(512), tb, 0, stream>>>(v, vb, nSm);
  transpose_convert<<<dim3(64, 64), tb, 0, stream>>>(Wk, WkT);
  transpose_convert<<<dim3(64, 64), tb, 0, stream>>>(Wv, WvT);
  gemm_kv<<<dim3(32, 8), tb, 0, stream>>>(kb, WkT, WvT, Kh, Vh);

  transpose_head<<<dim3(128), tb, 0, stream>>>(Vh, VTb);

  attn_kernel<<<dim3(16, 128), tb, 0, stream>>>(Qh, Kh, VTb, out, ctx);

  // out = ctx @ WoT
  gemm256<true><<<dim3(16, 32), tb5, 0, stream>>>(ctx, WoT, (void*)out);
}

// Round 4
// 1104.992 us; speedup vs baseline: 1.7222x; 1.0690x over previous
//
#include <hip/hip_runtime.h>
#include <hip/hip_bf16.h>

typedef unsigned short u16;
typedef unsigned int   u32;
typedef unsigned long long u64;
typedef __attribute__((ext_vector_type(8))) short short8;
typedef __attribute__((ext_vector_type(4))) float f32x4;

#define HID   4096
#define NHEAD 32
#define HD    128
#define NB    4
#define NSQ   2048
#define NSK   128
#define MROWS (NB*NSQ)   // 8192
#define KROWS (NB*NSK)   // 512

// ---------- helpers ----------
__device__ __forceinline__ u16 f2bf(float f) {           // RNE f32->bf16 (finite data)
  u32 u = __builtin_bit_cast(u32, f);
  u += 0x7fffu + ((u >> 16) & 1u);
  return (u16)(u >> 16);
}

__device__ __forceinline__ u64 pack4(float4 f) {
  return (u64)f2bf(f.x) | ((u64)f2bf(f.y) << 16) |
         ((u64)f2bf(f.z) << 32) | ((u64)f2bf(f.w) << 48);
}

__device__ __forceinline__ uint4 packu16x8(const u16* v) {
  uint4 o;
  o.x = (u32)v[0] | ((u32)v[1] << 16);
  o.y = (u32)v[2] | ((u32)v[3] << 16);
  o.z = (u32)v[4] | ((u32)v[5] << 16);
  o.w = (u32)v[6] | ((u32)v[7] << 16);
  return o;
}

__device__ __forceinline__ f32x4 mfma16(short8 a, short8 b, f32x4 c) {
  return __builtin_amdgcn_mfma_f32_16x16x32_bf16(a, b, c, 0, 0, 0);
}

__device__ __forceinline__ void gload_lds16(const u16* g, u16* l) {
  __builtin_amdgcn_global_load_lds((const __attribute__((address_space(1))) u32*)g,
                                   (__attribute__((address_space(3))) u32*)l, 16, 0, 0);
}

// ---------- elementwise f32 -> bf16 (one or two tensors per launch) ----------
__global__ __launch_bounds__(256) void convert_bf16(const float* __restrict__ in,
                                                    u16* __restrict__ out, long long n4)
{
  long long i = (long long)blockIdx.x * blockDim.x + threadIdx.x;
  const long long stride = (long long)gridDim.x * blockDim.x;
  for (; i < n4; i += stride) {
    float4 f = ((const float4*)in)[i];
    ((u64*)out)[i] = pack4(f);
  }
}

__global__ __launch_bounds__(256) void convert_bf16_x2(const float* __restrict__ in0,
                                                       u16* __restrict__ out0,
                                                       const float* __restrict__ in1,
                                                       u16* __restrict__ out1, long long n4)
{
  const float* in = blockIdx.y ? in1 : in0;
  u16* out = blockIdx.y ? out1 : out0;
  long long i = (long long)blockIdx.x * blockDim.x + threadIdx.x;
  const long long stride = (long long)gridDim.x * blockDim.x;
  for (; i < n4; i += stride) {
    float4 f = ((const float4*)in)[i];
    ((u64*)out)[i] = pack4(f);
  }
}

// ---------- W transpose + convert (two weights per launch): Wt[n][k] = bf16(W[k][n]) ----------
__global__ __launch_bounds__(256) void transpose_convert_x2(const float* __restrict__ W0,
                                                            u16* __restrict__ T0,
                                                            const float* __restrict__ W1,
                                                            u16* __restrict__ T1)
{
  const float* W = blockIdx.z ? W1 : W0;
  u16* Wt = blockIdx.z ? T1 : T0;
  __shared__ __align__(16) u16 tile[64][72];
  const int t = threadIdx.x;
  const int c0 = blockIdx.x * 64, r0 = blockIdx.y * 64;
  #pragma unroll
  for (int i = 0; i < 4; ++i) {
    int e = i * 1024 + t * 4;
    int rr = e >> 6, cc = e & 63;
    float4 f = *(const float4*)(W + (size_t)(r0 + rr) * HID + c0 + cc);
    *(u64*)&tile[rr][cc] = pack4(f);
  }
  __syncthreads();
  #pragma unroll
  for (int i = 0; i < 2; ++i) {
    int e = i * 2048 + t * 8;
    int cc = e >> 6, rr = e & 63;
    u16 vals[8];
    #pragma unroll
    for (int jj = 0; jj < 8; ++jj) vals[jj] = tile[rr + jj][cc];
    *(uint4*)(Wt + (size_t)(c0 + cc) * HID + r0 + rr) = packu16x8(vals);
  }
}

// ---------- per-head transpose of Vh ----------
__global__ __launch_bounds__(256) void transpose_head(const u16* __restrict__ Vh,
                                                      u16* __restrict__ VT)
{
  __shared__ __align__(16) u16 tile[128][136];
  const int t = threadIdx.x;
  const int bh = blockIdx.x;
  const int b = bh >> 5, h = bh & 31;
  #pragma unroll
  for (int i = 0; i < 8; ++i) {
    int e = i * 2048 + t * 8;
    int tr = e >> 7, d = e & 127;
    *(uint4*)&tile[tr][d] = *(const uint4*)(Vh + ((size_t)b * NSK + tr) * HID + h * HD + d);
  }
  __syncthreads();
  #pragma unroll
  for (int i = 0; i < 8; ++i) {
    int e = i * 2048 + t * 8;
    int d = e >> 7, tt = e & 127;
    u16 vals[8];
    #pragma unroll
    for (int jj = 0; jj < 8; ++jj) vals[jj] = tile[tt + jj][d];
    *(uint4*)(VT + ((size_t)bh * HD + d) * NSK + tt) = packu16x8(vals);
  }
}

// ====================== 256x256 8-phase GEMM (K = HID) ======================
// 8 waves (2Mx4N), BK=64, 128KB LDS dbuf, T2 slot-XOR swizzle, counted vmcnt,
// SINGLE barrier per phase (pre-MFMA); next phase's ds_reads/stages overlap
// the MFMA tail of the current phase across waves.

__device__ __forceinline__ short8 ldf(const u16* buf, int r, int cb) {
  return *(const short8*)(buf + r * 64 + (cb ^ ((r & 7) << 3)));
}

__device__ __forceinline__ void stage2(u16* dst, const u16* g, long off0, long off1, int tid) {
  gload_lds16(g + off0, dst + tid * 8);
  gload_lds16(g + off1, dst + 4096 + tid * 8);
}

// VM: vmcnt(N) in phase 4 (tile boundary); -1 = none.
template<int VM, bool S1, bool S2>
__device__ __forceinline__ void tile4(const u16* __restrict__ Ag, const u16* __restrict__ Bg,
                                      int kt, u16* Ac, u16* Bc, u16* Ao, u16* Bo,
                                      int wm, int wn, int g, int c16,
                                      long off0, long off1, int tid, f32x4 (&acc)[8][4])
{
  const int g8 = g * 8;
  short8 af[4][2], bf[4][2];

  // ---- phase 1: (Mlo, Nlo). reads: 8A + 4B ----
  #pragma unroll
  for (int i = 0; i < 4; ++i) {
    const int r = wm * 128 + i * 16 + c16;
    af[i][0] = ldf(Ac, r, g8); af[i][1] = ldf(Ac, r, 32 + g8);
  }
  #pragma unroll
  for (int j = 0; j < 2; ++j) {
    const int r = wn * 64 + j * 16 + c16;
    bf[j][0] = ldf(Bc, r, g8); bf[j][1] = ldf(Bc, r, 32 + g8);
  }
  if constexpr (S1) stage2(Ao + 8192, Ag + (size_t)128 * HID + kt + 64, off0, off1, tid);
  __builtin_amdgcn_s_barrier();
  asm volatile("s_waitcnt lgkmcnt(0)" ::: "memory");
  __builtin_amdgcn_sched_barrier(0);
  __builtin_amdgcn_s_setprio(1);
  #pragma unroll
  for (int i = 0; i < 4; ++i)
    #pragma unroll
    for (int j = 0; j < 2; ++j) {
      acc[i][j] = mfma16(af[i][0], bf[j][0], acc[i][j]);
      acc[i][j] = mfma16(af[i][1], bf[j][1], acc[i][j]);
    }
  __builtin_amdgcn_s_setprio(0);

  // ---- phase 2: (Mlo, Nhi). reads: 4B ----
  #pragma unroll
  for (int j = 2; j < 4; ++j) {
    const int r = wn * 64 + j * 16 + c16;
    bf[j][0] = ldf(Bc, r, g8); bf[j][1] = ldf(Bc, r, 32 + g8);
  }
  if constexpr (S1) stage2(Bo + 8192, Bg + (size_t)128 * HID + kt + 64, off0, off1, tid);
  __builtin_amdgcn_s_barrier();
  asm volatile("s_waitcnt lgkmcnt(0)" ::: "memory");
  __builtin_amdgcn_sched_barrier(0);
  __builtin_amdgcn_s_setprio(1);
  #pragma unroll
  for (int i = 0; i < 4; ++i)
    #pragma unroll
    for (int j = 2; j < 4; ++j) {
      acc[i][j] = mfma16(af[i][0], bf[j][0], acc[i][j]);
      acc[i][j] = mfma16(af[i][1], bf[j][1], acc[i][j]);
    }
  __builtin_amdgcn_s_setprio(0);

  // ---- phase 3: (Mhi, Nlo). reads: 8A. stage writes B-lo of T+2 (disjoint from
  //      any outstanding read region: B-hi reads drained per-wave at lgkm ph2) ----
  #pragma unroll
  for (int i = 0; i < 4; ++i) {
    const int r = wm * 128 + 64 + i * 16 + c16;
    af[i][0] = ldf(Ac, r, g8); af[i][1] = ldf(Ac, r, 32 + g8);
  }
  if constexpr (S2) stage2(Bc, Bg + kt + 128, off0, off1, tid);
  __builtin_amdgcn_s_barrier();
  asm volatile("s_waitcnt lgkmcnt(0)" ::: "memory");
  __builtin_amdgcn_sched_barrier(0);
  __builtin_amdgcn_s_setprio(1);
  #pragma unroll
  for (int i = 0; i < 4; ++i)
    #pragma unroll
    for (int j = 0; j < 2; ++j) {
      acc[4 + i][j] = mfma16(af[i][0], bf[j][0], acc[4 + i][j]);
      acc[4 + i][j] = mfma16(af[i][1], bf[j][1], acc[4 + i][j]);
    }
  __builtin_amdgcn_s_setprio(0);

  // ---- phase 4: (Mhi, Nhi). no reads. stage writes A-lo of T+2 (A-hi reads
  //      are the only possibly-outstanding A reads; disjoint region) ----
  if constexpr (S2) stage2(Ac, Ag + kt + 128, off0, off1, tid);
  if constexpr (VM == 4) {
    asm volatile("s_waitcnt vmcnt(4)" ::: "memory");
  } else if constexpr (VM == 0) {
    asm volatile("s_waitcnt vmcnt(0)" ::: "memory");
  }
  __builtin_amdgcn_s_barrier();
  __builtin_amdgcn_sched_barrier(0);
  __builtin_amdgcn_s_setprio(1);
  #pragma unroll
  for (int i = 0; i < 4; ++i)
    #pragma unroll
    for (int j = 2; j < 4; ++j) {
      acc[4 + i][j] = mfma16(af[i][0], bf[j][0], acc[4 + i][j]);
      acc[4 + i][j] = mfma16(af[i][1], bf[j][1], acc[4 + i][j]);
    }
  __builtin_amdgcn_s_setprio(0);
}

template<bool OUTF32>
__global__ __launch_bounds__(512, 2) void gemm256(const u16* __restrict__ A,
                                                  const u16* __restrict__ Bt,
                                                  void* __restrict__ Cv)
{
  __shared__ __align__(16) u16 As[2][16384];
  __shared__ __align__(16) u16 Bs[2][16384];
  const int tid = threadIdx.x;
  const int l = tid & 63, wv = tid >> 6;
  const int g = (l >> 4) & 3, c16 = l & 15;
  const int wm = wv >> 2, wn = wv & 3;

  const int ntn = gridDim.x;
  const int nwg = gridDim.x * gridDim.y;
  int wg = blockIdx.y * gridDim.x + blockIdx.x;
  wg = (wg & 7) * (nwg >> 3) + (wg >> 3);          // bijective XCD swizzle (nwg%8==0)
  const int m0 = (wg / ntn) * 256, n0 = (wg % ntn) * 256;

  const u16* Ag = A + (size_t)m0 * HID;
  const u16* Bg = Bt + (size_t)n0 * HID;
  // per-thread staging source offsets (inverse slot-XOR swizzle)
  const long off0 = (long)(tid >> 3) * HID + (((tid & 7) ^ ((tid >> 3) & 7)) * 8);
  const long off1 = off0 + (long)64 * HID;

  f32x4 acc[8][4] = {};

  // prologue: T0.B0, T0.A0, T0.A1, T0.B1, T1.B0, T1.A0 ; vmcnt(4) -> T0 landed
  stage2(&Bs[0][0],    Bg,                     off0, off1, tid);
  stage2(&As[0][0],    Ag,                     off0, off1, tid);
  stage2(&As[0][8192], Ag + (size_t)128 * HID, off0, off1, tid);
  stage2(&Bs[0][8192], Bg + (size_t)128 * HID, off0, off1, tid);
  stage2(&Bs[1][0],    Bg + 64,                off0, off1, tid);
  stage2(&As[1][0],    Ag + 64,                off0, off1, tid);
  asm volatile("s_waitcnt vmcnt(4)" ::: "memory");
  __builtin_amdgcn_sched_barrier(0);
  __builtin_amdgcn_s_barrier();

  constexpr int NT = HID / 64;   // 64
  int T = 0;
  for (; T < NT - 3; T += 2) {
    tile4<4, true, true>(Ag, Bg, T * 64,      &As[0][0], &Bs[0][0], &As[1][0], &Bs[1][0],
                         wm, wn, g, c16, off0, off1, tid, acc);
    tile4<4, true, true>(Ag, Bg, T * 64 + 64, &As[1][0], &Bs[1][0], &As[0][0], &Bs[0][0],
                         wm, wn, g, c16, off0, off1, tid, acc);
  }
  tile4<0, true, false>(Ag, Bg, (NT - 2) * 64, &As[0][0], &Bs[0][0], &As[1][0], &Bs[1][0],
                        wm, wn, g, c16, off0, off1, tid, acc);
  tile4<-1, false, false>(Ag, Bg, (NT - 1) * 64, &As[1][0], &Bs[1][0], &As[0][0], &Bs[0][0],
                          wm, wn, g, c16, off0, off1, tid, acc);

  #pragma unroll
  for (int mi = 0; mi < 8; ++mi)
    #pragma unroll
    for (int j = 0; j < 4; ++j)
      #pragma unroll
      for (int rr = 0; rr < 4; ++rr) {
        const size_t row = (size_t)m0 + wm * 128 + mi * 16 + g * 4 + rr;
        const size_t col = (size_t)n0 + wn * 64 + j * 16 + c16;
        if constexpr (OUTF32)
          ((float*)Cv)[row * HID + col] = acc[mi][j][rr];
        else
          ((u16*)Cv)[row * HID + col] = f2bf(acc[mi][j][rr]);
      }
}

// ---------- fused K+V projection: A = [kb;vb] [1024][HID], 128x128 2-phase ----------
__global__ __launch_bounds__(256) void gemm_kv(const u16* __restrict__ A,
                                               const u16* __restrict__ WkTp,
                                               const u16* __restrict__ WvTp,
                                               u16* __restrict__ Kh,
                                               u16* __restrict__ Vh)
{
  __shared__ __align__(16) u16 As_[128 * 64];
  __shared__ __align__(16) u16 Bs_[128 * 64];
  const int t = threadIdx.x;
  const int w = t >> 6, l = t & 63;
  const int g = l >> 4, c16 = l & 15;
  const int m0 = blockIdx.y * 128, n0 = blockIdx.x * 128;
  const u16* Bt = (m0 < 512) ? WkTp : WvTp;
  u16* C = (m0 < 512) ? Kh : Vh;
  const int mr0 = m0 & 511;
  const int wm = (w >> 1) * 64, wn = (w & 1) * 64;

  f32x4 acc[4][4] = {};
  for (int kt = 0; kt < HID; kt += 64) {
    #pragma unroll
    for (int i = 0; i < 4; ++i) {
      int e = i * 2048 + t * 8;
      int rr = e >> 6, cc = e & 63;
      gload_lds16(A + (size_t)(m0 + rr) * HID + kt + cc, As_ + e);
      gload_lds16(Bt + (size_t)(n0 + rr) * HID + kt + cc, Bs_ + e);
    }
    __syncthreads();
    #pragma unroll
    for (int ks = 0; ks < 2; ++ks) {
      const int ko = ks * 32 + g * 8;
      short8 af2[4], bf2[4];
      #pragma unroll
      for (int i = 0; i < 4; ++i)
        af2[i] = *(const short8*)(As_ + (wm + i * 16 + c16) * 64 + ko);
      #pragma unroll
      for (int j = 0; j < 4; ++j)
        bf2[j] = *(const short8*)(Bs_ + (wn + j * 16 + c16) * 64 + ko);
      #pragma unroll
      for (int i = 0; i < 4; ++i)
        #pragma unroll
        for (int j = 0; j < 4; ++j)
          acc[i][j] = mfma16(af2[i], bf2[j], acc[i][j]);
    }
    __syncthreads();
  }
  #pragma unroll
  for (int i = 0; i < 4; ++i)
    #pragma unroll
    for (int j = 0; j < 4; ++j)
      #pragma unroll
      for (int rr = 0; rr < 4; ++rr)
        C[(size_t)(mr0 + wm + i * 16 + g * 4 + rr) * HID + n0 + wn + j * 16 + c16] =
            f2bf(acc[i][j][rr]);
}

// ---------- fused attention ----------
__global__ __launch_bounds__(256) void attn_kernel(const u16*  __restrict__ Qh,
                                                   const u16*  __restrict__ Kh,
                                                   const u16*  __restrict__ VT,
                                                   const float* __restrict__ Rh,
                                                   u16* __restrict__ ctx)
{
  __shared__ __align__(16) u16 Plds[4][32][136];
  const int t = threadIdx.x;
  const int w = t >> 6, l = t & 63;
  const int g = l >> 4, c = l & 15;
  const int qc = blockIdx.x;
  const int bh = blockIdx.y;
  const int b = bh >> 5, h = bh & 31;
  const size_t qrow0 = (size_t)b * NSQ + qc * 128 + w * 32;
  const float SCALE = 0.08838834764831845f;  // 1/sqrt(128)

  f32x4 s[2][8] = {};
  #pragma unroll
  for (int ks = 0; ks < 4; ++ks) {
    const int ko = ks * 32 + g * 8;
    short8 af[2];
    #pragma unroll
    for (int i = 0; i < 2; ++i)
      af[i] = *(const short8*)(Qh + (qrow0 + i * 16 + c) * HID + h * HD + ko);
    #pragma unroll
    for (int j = 0; j < 8; ++j) {
      short8 bfr = *(const short8*)(Kh + ((size_t)b * NSK + j * 16 + c) * HID + h * HD + ko);
      s[0][j] = mfma16(af[0], bfr, s[0][j]);
      s[1][j] = mfma16(af[1], bfr, s[1][j]);
    }
  }

  float rinv[2][4];
  #pragma unroll
  for (int i = 0; i < 2; ++i) {
    #pragma unroll
    for (int rr = 0; rr < 4; ++rr) {
      const size_t qr = qrow0 + i * 16 + g * 4 + rr;
      float vmax = -3.0e38f;
      #pragma unroll
      for (int j = 0; j < 8; ++j) {
        float bias = Rh[qr * HID + h * HD + j * 16 + c];
        float sv = s[i][j][rr] * SCALE + bias;
        s[i][j][rr] = sv;
        vmax = fmaxf(vmax, sv);
      }
      #pragma unroll
      for (int m = 1; m < 16; m <<= 1) vmax = fmaxf(vmax, __shfl_xor(vmax, m));
      float ssum = 0.f;
      #pragma unroll
      for (int j = 0; j < 8; ++j) {
        float p = __expf(s[i][j][rr] - vmax);
        s[i][j][rr] = p;
        ssum += p;
      }
      #pragma unroll
      for (int m = 1; m < 16; m <<= 1) ssum += __shfl_xor(ssum, m);
      rinv[i][rr] = 1.f / ssum;
    }
  }

  #pragma unroll
  for (int i = 0; i < 2; ++i)
    #pragma unroll
    for (int j = 0; j < 8; ++j)
      #pragma unroll
      for (int rr = 0; rr < 4; ++rr)
        Plds[w][i * 16 + g * 4 + rr][j * 16 + c] = f2bf(s[i][j][rr]);
  __syncthreads();

  #pragma unroll
  for (int i = 0; i < 2; ++i) {
    f32x4 o[8] = {};
    #pragma unroll
    for (int ks = 0; ks < 4; ++ks) {
      const int ko = ks * 32 + g * 8;
      short8 pa = *(const short8*)(&Plds[w][i * 16 + c][ko]);
      #pragma unroll
      for (int j = 0; j < 8; ++j) {
        short8 bv = *(const short8*)(VT + ((size_t)bh * HD + j * 16 + c) * NSK + ko);
        o[j] = mfma16(pa, bv, o[j]);
      }
    }
    #pragma unroll
    for (int j = 0; j < 8; ++j)
      #pragma unroll
      for (int rr = 0; rr < 4; ++rr) {
        const size_t row = qrow0 + i * 16 + g * 4 + rr;
        ctx[row * HID + h * HD + j * 16 + c] = f2bf(o[j][rr] * rinv[i][rr]);
      }
  }
}

// ---------- launch ----------
extern "C" void kernel_launch(void* const* d_in, const int* in_sizes, int n_in,
                              void* d_out, int out_size, void* d_ws, size_t ws_size,
                              hipStream_t stream)
{
  const float* q  = (const float*)d_in[0];
  const float* k  = (const float*)d_in[1];
  const float* v  = (const float*)d_in[2];
  const float* r  = (const float*)d_in[3];
  const float* Wq = (const float*)d_in[4];
  const float* Wk = (const float*)d_in[5];
  const float* Wv = (const float*)d_in[6];
  const float* Wo = (const float*)d_in[7];
  float* out = (float*)d_out;

  // Workspace (268 MB, lifetime-aliased):
  //  [0,32)    WoT (whole run)      [32,96)  Qh        [96,100) Kh
  //  [100,104) Vh                   [104,108) VT
  //  [108,172) ctx  (kb@108, vb@112 die before attn writes ctx)
  //  [172,236) Sb (q-bf16 then r-bf16); after Rh-GEMM: WkT@172, WvT@204
  //  [236,268) WqT
  char* ws = (char*)d_ws;
  #define WSMB(x) ((size_t)(x) << 20)
  u16* WoT = (u16*)(ws + WSMB(0));
  u16* Qh  = (u16*)(ws + WSMB(32));
  u16* Kh  = (u16*)(ws + WSMB(96));
  u16* Vh  = (u16*)(ws + WSMB(100));
  u16* VTb = (u16*)(ws + WSMB(104));
  u16* ctx = (u16*)(ws + WSMB(108));
  u16* kb  = (u16*)(ws + WSMB(108));
  u16* vb  = (u16*)(ws + WSMB(112));
  u16* Sb  = (u16*)(ws + WSMB(172));
  u16* WkT = (u16*)(ws + WSMB(172));
  u16* WvT = (u16*)(ws + WSMB(204));
  u16* WqT = (u16*)(ws + WSMB(236));
  const size_t needed = WSMB(268);
  if (ws_size < needed) return;

  dim3 tb(256);
  dim3 tb5(512);
  const long long nBig = (long long)MROWS * HID / 4;
  const long long nSm  = (long long)KROWS * HID / 4;

  // Wo^T, Wq^T (one dual launch)
  transpose_convert_x2<<<dim3(64, 64, 2), tb, 0, stream>>>(Wo, WoT, Wq, WqT);

  // k,v -> bf16 (one dual launch)
  convert_bf16_x2<<<dim3(512, 2), tb, 0, stream>>>(k, kb, v, vb, nSm);

  // Qh = bf16(q) @ WqT
  convert_bf16<<<dim3(2048), tb, 0, stream>>>(q, Sb, nBig);
  gemm256<false><<<dim3(16, 32), tb5, 0, stream>>>(Sb, WqT, (void*)Qh);

  // Rh = bf16(r) @ WoT -> d_out (f32 bias)
  convert_bf16<<<dim3(2048), tb, 0, stream>>>(r, Sb, nBig);
  gemm256<true><<<dim3(16, 32), tb5, 0, stream>>>(Sb, WoT, (void*)out);

  // Wk^T, Wv^T (Sb region is free now)
  transpose_convert_x2<<<dim3(64, 64, 2), tb, 0, stream>>>(Wk, WkT, Wv, WvT);
  gemm_kv<<<dim3(32, 8), tb, 0, stream>>>(kb, WkT, WvT, Kh, Vh);

  transpose_head<<<dim3(128), tb, 0, stream>>>(Vh, VTb);

  attn_kernel<<<dim3(16, 128), tb, 0, stream>>>(Qh, Kh, VTb, out, ctx);

  // out = ctx @ WoT
  gemm256<true><<<dim3(16, 32), tb5, 0, stream>>>(ctx, WoT, (void*)out);
}